// Round 6
// baseline (253.274 us; speedup 1.0000x reference)
//
#include <hip/hip_runtime.h>
#include <hip/hip_bf16.h>

using bf16 = __hip_bfloat16;
using short8 = __attribute__((ext_vector_type(8))) short;
using f32x4  = __attribute__((ext_vector_type(4))) float;
typedef unsigned int u32;

#define LAT_ 1536

__device__ __forceinline__ void glds16(const bf16* g, bf16* l) {
  __builtin_amdgcn_global_load_lds(
      (const __attribute__((address_space(1))) void*)g,
      (__attribute__((address_space(3))) void*)l, 16, 0, 0);
}
__device__ __forceinline__ float b2f(bf16 x) { return __bfloat162float(x); }
__device__ __forceinline__ bf16 f2b(float x) { return __float2bfloat16(x); }

// ---------------- NCHW fp32 -> NHWC bf16 tile ----------------
template<int C, int W>
__device__ __forceinline__ void trans_tile(const float* __restrict__ src, bf16* __restrict__ dst,
                                           int b, int hw0, int c0, bf16 (*tile)[72], int t) {
  constexpr int HW = W * W;
  {
    int cl = t >> 2, h0 = (t & 3) * 16;
    const float* sp = src + (long)(b * C + c0 + cl) * HW + hw0 + h0;
    #pragma unroll
    for (int k = 0; k < 16; k += 4) {
      float4 v = *(const float4*)(sp + k);
      tile[h0 + k + 0][cl] = f2b(v.x);
      tile[h0 + k + 1][cl] = f2b(v.y);
      tile[h0 + k + 2][cl] = f2b(v.z);
      tile[h0 + k + 3][cl] = f2b(v.w);
    }
  }
  __syncthreads();
  {
    int hwl = t >> 2, cc = (t & 3) * 16;
    bf16* dp = dst + ((long)b * HW + hw0 + hwl) * C + c0 + cc;
    #pragma unroll
    for (int k = 0; k < 16; k += 2) {
      __hip_bfloat162 pr;
      pr.x = tile[hwl][cc + k];
      pr.y = tile[hwl][cc + k + 1];
      *(__hip_bfloat162*)(dp + k) = pr;
    }
  }
}

// ---------------- fused prep ----------------
// [0,18432) packA | [18432,19456) pcw | [19456,19584) pow | [19584,19600) T5
// [19600,19602) bn | [19602,19610) u | [19610] gconst | [19611,19643) gacc=0
// [19643,22651) transposes
__global__ __launch_bounds__(256) void prep_k(
    const float* __restrict__ g_iw, const float* __restrict__ p_iw,
    const float* __restrict__ p_cw, const float* __restrict__ p_ow, const float* __restrict__ f5,
    const float* __restrict__ g_bg, const float* __restrict__ g_bb, const float* __restrict__ g_bm,
    const float* __restrict__ g_bv, const float* __restrict__ p_bg, const float* __restrict__ p_bb,
    const float* __restrict__ p_bm, const float* __restrict__ p_bv,
    const float* __restrict__ g_ib, const float* __restrict__ p_ib, const float* __restrict__ p_cb,
    const float* __restrict__ g_ow, const float* __restrict__ g_cw,
    const float* __restrict__ g_cb, const float* __restrict__ g_ob,
    const float* __restrict__ f0, const float* __restrict__ f1, const float* __restrict__ f2,
    const float* __restrict__ f3, const float* __restrict__ f4,
    bf16* __restrict__ Wp, bf16* __restrict__ pcw16, bf16* __restrict__ pow16,
    bf16* __restrict__ T5, float* __restrict__ bnp, float* __restrict__ u,
    float* __restrict__ gacc,
    bf16* __restrict__ T0, bf16* __restrict__ T1, bf16* __restrict__ T2,
    bf16* __restrict__ T3, bf16* __restrict__ T4) {
  __shared__ bf16 tile[64][72];
  __shared__ float red[256];
  int B = blockIdx.x, t = threadIdx.x;
  if (B < 18432) {
    int seg = B / 3072;
    int idx = (B % 3072) * 256 + t;
    if (idx < 512 * 1536) {
      int r = idx / 1536, c = idx % 1536;
      const float* src; int co;
      switch (seg) {
        case 0: src = g_iw; co = 0;    break;
        case 1: src = g_iw; co = 1536; break;
        case 2: src = p_iw; co = 0;    break;
        case 3: src = p_iw; co = 1536; break;
        case 4: src = g_iw; co = 3072; break;
        default: src = p_iw; co = 3072; break;
      }
      Wp[(long)seg * 512 * 1536 + idx] = f2b(src[(long)r * 4608 + co + c]);
    }
    return;
  }
  if (B < 19456) { int idx = (B - 18432) * 256 + t; pcw16[idx] = f2b(p_cw[idx]); return; }
  if (B < 19584) { int idx = (B - 19456) * 256 + t; pow16[idx] = f2b(p_ow[idx]); return; }
  if (B < 19600) { int idx = (B - 19584) * 256 + t; T5[idx] = f2b(f5[idx]); return; }
  if (B < 19602) {
    int k = (B - 19600) * 256 + t;
    if (k < 512) {
      float sg = g_bg[k] / sqrtf(g_bv[k] + 1e-5f);
      bnp[k] = sg; bnp[512 + k] = g_bb[k] - g_bm[k] * sg;
      float sp = p_bg[k] / sqrtf(p_bv[k] + 1e-5f);
      bnp[1024 + k] = sp; bnp[1536 + k] = p_bb[k] - p_bm[k] * sp;
      bnp[2048 + k] = g_ib[k]; bnp[2560 + k] = p_ib[k];
      bnp[3584 + k] = p_cb[k];
    }
    return;
  }
  if (B < 19610) {                      // u[k] = sum_o g_ow[o]*g_cw[o*512+k]
    __shared__ float ured[4][64];
    int k0 = (B - 19602) * 64;
    int kk = t & 63, part = t >> 6;
    int k = k0 + kk;
    float s = 0.f;
    for (int o = part * 128; o < part * 128 + 128; ++o)
      s = fmaf(g_ow[o], g_cw[o * 512 + k], s);
    ured[part][kk] = s;
    __syncthreads();
    if (part == 0) u[k] = ured[0][kk] + ured[1][kk] + ured[2][kk] + ured[3][kk];
    return;
  }
  if (B == 19610) {                     // gconst = sum g_ow*g_cb + g_ob
    red[t] = g_ow[t] * g_cb[t] + g_ow[t + 256] * g_cb[t + 256];
    __syncthreads();
    for (int off = 128; off; off >>= 1) {
      if (t < off) red[t] += red[t + off];
      __syncthreads();
    }
    if (t == 0) bnp[3072] = red[0] + g_ob[0];
    return;
  }
  if (B < 19643) { int idx = (B - 19611) * 256 + t; gacc[idx] = 0.f; return; }
  {
    int q = B - 19643;
    int b = q / 376, tt = q % 376;
    if (tt < 256)      trans_tile<64, 128>(f0, T0, b, tt * 64, 0, tile, t);
    else if (tt < 320) trans_tile<64, 64 >(f1, T1, b, (tt - 256) * 64, 0, tile, t);
    else if (tt < 352) { int z = tt - 320; trans_tile<128, 32>(f2, T2, b, (z & 15) * 64, (z >> 4) * 64, tile, t); }
    else if (tt < 368) { int z = tt - 352; trans_tile<256, 16>(f3, T3, b, (z & 3) * 64, (z >> 2) * 64, tile, t); }
    else               { int z = tt - 368; trans_tile<512, 8 >(f4, T4, b, 0, z * 64, tile, t); }
  }
}

// ---------------- sampling ----------------
__device__ __forceinline__ float blo(u32 r) { return __uint_as_float(r << 16); }
__device__ __forceinline__ float bhi(u32 r) { return __uint_as_float(r & 0xffff0000u); }

template<int C, int W>
__device__ __forceinline__ void proc2(const bf16* __restrict__ T, int b,
    const float* MX, const float* MY, bf16* __restrict__ Sb, int koff, int t) {
  constexpr int C2 = C / 2, HW = W * W;
  const bf16* Tb = T + (long)b * HW * C;
  for (int idx = t; idx < 16 * C2; idx += 256) {
    int q = idx / C2, c2 = idx % C2;
    float x = MX[q], y = MY[q];
    float fx = fminf(fmaxf(x * ((float)W / 256.f) - 0.5f, 0.f), (float)(W - 1));
    float fy = fminf(fmaxf(y * ((float)W / 256.f) - 0.5f, 0.f), (float)(W - 1));
    float x0f = floorf(fx), y0f = floorf(fy);
    float wx = fx - x0f, wy = fy - y0f;
    int x0 = (int)x0f, y0 = (int)y0f;
    int x1 = min(x0 + 1, W - 1), y1 = min(y0 + 1, W - 1);
    u32 r00 = *(const u32*)&Tb[(y0 * W + x0) * C + 2 * c2];
    u32 r01 = *(const u32*)&Tb[(y0 * W + x1) * C + 2 * c2];
    u32 r10 = *(const u32*)&Tb[(y1 * W + x0) * C + 2 * c2];
    u32 r11 = *(const u32*)&Tb[(y1 * W + x1) * C + 2 * c2];
    float w00 = (1.f - wx) * (1.f - wy), w01 = wx * (1.f - wy);
    float w10 = (1.f - wx) * wy,        w11 = wx * wy;
    float vlo = blo(r00) * w00 + blo(r01) * w01 + blo(r10) * w10 + blo(r11) * w11;
    float vhi = bhi(r00) * w00 + bhi(r01) * w01 + bhi(r10) * w10 + bhi(r11) * w11;
    __hip_bfloat162 pr;
    pr.x = f2b(vlo); pr.y = f2b(vhi);
    *(__hip_bfloat162*)&Sb[(long)q * LAT_ + koff + 2 * c2] = pr;
  }
}

__global__ __launch_bounds__(256) void sample5_k(
    const bf16* __restrict__ T0, const bf16* __restrict__ T1, const bf16* __restrict__ T2,
    const bf16* __restrict__ T3, const bf16* __restrict__ T4, const bf16* __restrict__ T5,
    const float* __restrict__ P, bf16* __restrict__ Sball) {
  int b = blockIdx.z, p0 = blockIdx.x * 16, lvl = blockIdx.y, t = threadIdx.x;
  __shared__ float Px[32], Py[32], MX[16], MY[16];
  if (t < 32) { Px[t] = P[(b * 32 + t) * 2]; Py[t] = P[(b * 32 + t) * 2 + 1]; }
  __syncthreads();
  if (t < 16) {
    int m = p0 + t;
    float x, y;
    if (m < 32) { x = Px[m]; y = Py[m]; }
    else { int ij = m - 32, i = ij >> 5, j = ij & 31;
           x = 0.5f * (Px[i] + Px[j]); y = 0.5f * (Py[i] + Py[j]); }
    MX[t] = x; MY[t] = y;
  }
  __syncthreads();
  bf16* Sb = Sball + ((long)b * 1056 + p0) * LAT_;
  switch (lvl) {
    case 0: proc2<64, 128>(T0, b, MX, MY, Sb, 0,    t); break;
    case 1: proc2<64, 64 >(T1, b, MX, MY, Sb, 64,   t); break;
    case 2: proc2<128, 32>(T2, b, MX, MY, Sb, 128,  t); break;
    case 3: proc2<256, 16>(T3, b, MX, MY, Sb, 256,  t); break;
    case 4: proc2<512, 8 >(T4, b, MX, MY, Sb, 512,  t); break;
    default:
      for (int idx = t; idx < 16 * 256; idx += 256) {
        int q = idx >> 8, c2 = idx & 255;
        *(__hip_bfloat162*)&Sb[(long)q * LAT_ + 1024 + 2 * c2] =
            *(const __hip_bfloat162*)&T5[b * 512 + 2 * c2];
      }
  }
}

// ---------------- node GEMM: A4[b][32][2048] ----------------
__global__ __launch_bounds__(256) void nodegemm_k(
    const bf16* __restrict__ Sball, const bf16* __restrict__ Wp, float* __restrict__ A4) {
  int b = blockIdx.y;
  int n0 = blockIdx.x * 64;
  int t = threadIdx.x, w = t >> 6, lane = t & 63;
  int nn = n0 + w * 16;
  int frow = lane & 15, fko = (lane >> 4) * 8;
  const bf16* Ab = Sball + (long)b * 1056 * LAT_;
  f32x4 acc[2] = {};
  for (int kb = 0; kb < LAT_; kb += 32) {
    short8 bq = *(const short8*)&Wp[(long)(nn + frow) * LAT_ + kb + fko];
    #pragma unroll
    for (int i = 0; i < 2; ++i) {
      short8 aq = *(const short8*)&Ab[(long)(i * 16 + frow) * LAT_ + kb + fko];
      acc[i] = __builtin_amdgcn_mfma_f32_16x16x32_bf16(aq, bq, acc[i], 0, 0, 0);
    }
  }
  #pragma unroll
  for (int i = 0; i < 2; ++i)
    #pragma unroll
    for (int r = 0; r < 4; ++r) {
      int m = i * 16 + (lane >> 4) * 4 + r;
      int n = nn + (lane & 15);
      A4[(long)b * 65536 + m * 2048 + n] = acc[i][r];
    }
}

// ---------------- edge GEMM: M=1024, N=1024 (g|p), K=1536 ----------------
// 128x128, BK=64, dbuf + counted vmcnt (R5 sync structure, verified) with
// SPLIT MFMA: h0-MFMA overlaps h1 ds_reads (compiler auto-waits h0 only);
// h1-MFMA overlaps STAGE issue/flight. Same barrier count & vmcnt protocol
// as R5 -- only instruction placement between waits changed.
__global__ __launch_bounds__(256) void edge_k(
    const bf16* __restrict__ Sball, const bf16* __restrict__ WpE,
    const float* __restrict__ bnp, const float* __restrict__ A4,
    const float* __restrict__ u, const float* __restrict__ g_ow,
    bf16* __restrict__ XFh, bf16* __restrict__ DH, float* __restrict__ gacc) {
  int b = blockIdx.z;
  int m0 = blockIdx.x * 128, n0 = blockIdx.y * 128;
  const bf16* A = Sball + (long)b * 1056 * LAT_ + 32 * LAT_;
  __shared__ bf16 Ash[2][128 * 64];
  __shared__ bf16 Bsh[2][128 * 64];
  int t = threadIdx.x, w = t >> 6, lane = t & 63;
  int mh = (w & 1) * 64, nh = (w >> 1) * 64;
  int frow = lane & 15, kq = lane >> 4;
  int srow = w * 8 + (lane >> 3), schunk = lane & 7;   // stage row/chunk
  int rx7 = frow & 7;                                  // row&7 for frag rows
  f32x4 acc[4][4] = {};

  auto STAGE = [&](int buf, int kt) {
    int kb = kt * 64;
    #pragma unroll
    for (int q = 0; q < 4; ++q) {
      int ra = q * 32 + srow;
      int sc = (schunk ^ (ra & 7)) * 8;                // inverse-swizzled src col
      glds16(&A[(long)(m0 + ra) * LAT_ + kb + sc],   &Ash[buf][ra * 64 + schunk * 8]);
      glds16(&WpE[(long)(n0 + ra) * LAT_ + kb + sc], &Bsh[buf][ra * 64 + schunk * 8]);
    }
  };

  STAGE(0, 0);
  STAGE(1, 1);
  asm volatile("s_waitcnt vmcnt(8)" ::: "memory");     // tile 0 resident
  __builtin_amdgcn_sched_barrier(0);
  __builtin_amdgcn_s_barrier();
  #pragma unroll 1
  for (int kt = 0; kt < 24; ++kt) {
    int c = kt & 1;
    short8 af[2][4], bq[2][4];
    #pragma unroll
    for (int h = 0; h < 2; ++h) {
      int s8 = (((h * 4 + kq) ^ rx7) << 3);            // swizzled read offset
      #pragma unroll
      for (int i = 0; i < 4; ++i)
        af[h][i] = *(const short8*)&Ash[c][(mh + i * 16 + frow) * 64 + s8];
      #pragma unroll
      for (int j = 0; j < 4; ++j)
        bq[h][j] = *(const short8*)&Bsh[c][(nh + j * 16 + frow) * 64 + s8];
    }
    __builtin_amdgcn_sched_barrier(0);                 // reads issued first
    __builtin_amdgcn_s_setprio(1);
    #pragma unroll
    for (int i = 0; i < 4; ++i)                        // h0 MFMA ∥ h1 ds_reads
      #pragma unroll
      for (int j = 0; j < 4; ++j)
        acc[i][j] = __builtin_amdgcn_mfma_f32_16x16x32_bf16(af[0][i], bq[0][j], acc[i][j], 0, 0, 0);
    __builtin_amdgcn_s_setprio(0);
    asm volatile("s_waitcnt lgkmcnt(0)" ::: "memory"); // my reads of buf c done
    __builtin_amdgcn_sched_barrier(0);
    __builtin_amdgcn_s_barrier();                      // ALL waves done reading buf c
    if (kt + 2 < 24) STAGE(c, kt + 2);                 // overwrite buf c (async)
    __builtin_amdgcn_sched_barrier(0);
    __builtin_amdgcn_s_setprio(1);
    #pragma unroll
    for (int i = 0; i < 4; ++i)                        // h1 MFMA ∥ staging
      #pragma unroll
      for (int j = 0; j < 4; ++j)
        acc[i][j] = __builtin_amdgcn_mfma_f32_16x16x32_bf16(af[1][i], bq[1][j], acc[i][j], 0, 0, 0);
    __builtin_amdgcn_s_setprio(0);
    if (kt < 23) {
      if (kt + 2 < 24) {
        asm volatile("s_waitcnt vmcnt(8)" ::: "memory");  // tile kt+1 resident
      } else {
        asm volatile("s_waitcnt vmcnt(0)" ::: "memory");  // last tile resident
      }
      __builtin_amdgcn_sched_barrier(0);
      __builtin_amdgcn_s_barrier();
    }
  }
  if (n0 < 512) {                                     // gate half
    float pg[16];
    #pragma unroll
    for (int z = 0; z < 16; ++z) pg[z] = 0.f;
    #pragma unroll
    for (int i = 0; i < 4; ++i) {
      #pragma unroll
      for (int j = 0; j < 4; ++j) {
        int n = n0 + nh + j * 16 + (lane & 15);
        float gw = g_ow[n], uu = u[n];
        float sc2 = bnp[n], sh = bnp[512 + n], ib = bnp[2048 + n];
        #pragma unroll
        for (int r = 0; r < 4; ++r) {
          int m = m0 + mh + i * 16 + (lane >> 4) * 4 + r;
          float v = acc[i][j][r] + ib
                  + A4[((long)b * 32 + (m >> 5)) * 2048 + n]
                  + A4[((long)b * 32 + (m & 31)) * 2048 + 512 + n];
          float d = fmaxf(fmaf(v, sc2, sh), 0.f);
          pg[i * 4 + r] += gw * v + uu * d;
        }
      }
    }
    #pragma unroll
    for (int z = 0; z < 16; ++z) {
      float v = pg[z];
      v += __shfl_xor(v, 1, 16);
      v += __shfl_xor(v, 2, 16);
      v += __shfl_xor(v, 4, 16);
      v += __shfl_xor(v, 8, 16);
      pg[z] = v;
    }
    if ((lane & 15) == 0) {
      #pragma unroll
      for (int z = 0; z < 16; ++z) {
        int m = m0 + mh + (z >> 2) * 16 + (lane >> 4) * 4 + (z & 3);
        atomicAdd(&gacc[(long)b * 1024 + m], pg[z]);
      }
    }
  } else {                                            // p half: store compact
    #pragma unroll
    for (int i = 0; i < 4; ++i) {
      #pragma unroll
      for (int j = 0; j < 4; ++j) {
        int n = n0 + nh + j * 16 + (lane & 15);
        int np = n - 512;
        float sc2 = bnp[1024 + np], sh = bnp[1536 + np], ib = bnp[2048 + n];
        #pragma unroll
        for (int r = 0; r < 4; ++r) {
          int m = m0 + mh + i * 16 + (lane >> 4) * 4 + r;
          float v = acc[i][j][r] + ib
                  + A4[((long)b * 32 + (m >> 5)) * 2048 + 1024 + np]
                  + A4[((long)b * 32 + (m & 31)) * 2048 + 1536 + np];
          long e = ((long)b * 1024 + m) * 512 + np;
          XFh[e] = f2b(v);
          DH[e]  = f2b(fmaxf(fmaf(v, sc2, sh), 0.f));
        }
      }
    }
  }
}

// ---------------- chorus-p (compact), Yp16 = XFh + pcw @ DH + p_cb ----------------
// Same dbuf + counted-vmcnt + split-MFMA schedule as edge_k (K=512 -> 8 tiles).
__global__ __launch_bounds__(256) void chorus_k(
    const bf16* __restrict__ DH, const bf16* __restrict__ pcw16,
    const float* __restrict__ bnp, const bf16* __restrict__ XFh,
    bf16* __restrict__ Yp16) {
  int b = blockIdx.z;
  int m0 = blockIdx.x * 128, n0 = blockIdx.y * 128;
  const bf16* A = DH + (long)b * 1024 * 512;
  __shared__ bf16 Ash[2][128 * 64];
  __shared__ bf16 Bsh[2][128 * 64];
  int t = threadIdx.x, w = t >> 6, lane = t & 63;
  int mh = (w & 1) * 64, nh = (w >> 1) * 64;
  int frow = lane & 15, kq = lane >> 4;
  int srow = w * 8 + (lane >> 3), schunk = lane & 7;
  int rx7 = frow & 7;
  f32x4 acc[4][4] = {};

  auto STAGE = [&](int buf, int kt) {
    int kb = kt * 64;
    #pragma unroll
    for (int q = 0; q < 4; ++q) {
      int ra = q * 32 + srow;
      int sc = (schunk ^ (ra & 7)) * 8;
      glds16(&A[(long)(m0 + ra) * 512 + kb + sc],     &Ash[buf][ra * 64 + schunk * 8]);
      glds16(&pcw16[(long)(n0 + ra) * 512 + kb + sc], &Bsh[buf][ra * 64 + schunk * 8]);
    }
  };

  STAGE(0, 0);
  STAGE(1, 1);
  asm volatile("s_waitcnt vmcnt(8)" ::: "memory");
  __builtin_amdgcn_sched_barrier(0);
  __builtin_amdgcn_s_barrier();
  #pragma unroll 1
  for (int kt = 0; kt < 8; ++kt) {
    int c = kt & 1;
    short8 af[2][4], bq[2][4];
    #pragma unroll
    for (int h = 0; h < 2; ++h) {
      int s8 = (((h * 4 + kq) ^ rx7) << 3);
      #pragma unroll
      for (int i = 0; i < 4; ++i)
        af[h][i] = *(const short8*)&Ash[c][(mh + i * 16 + frow) * 64 + s8];
      #pragma unroll
      for (int j = 0; j < 4; ++j)
        bq[h][j] = *(const short8*)&Bsh[c][(nh + j * 16 + frow) * 64 + s8];
    }
    __builtin_amdgcn_sched_barrier(0);
    __builtin_amdgcn_s_setprio(1);
    #pragma unroll
    for (int i = 0; i < 4; ++i)
      #pragma unroll
      for (int j = 0; j < 4; ++j)
        acc[i][j] = __builtin_amdgcn_mfma_f32_16x16x32_bf16(af[0][i], bq[0][j], acc[i][j], 0, 0, 0);
    __builtin_amdgcn_s_setprio(0);
    asm volatile("s_waitcnt lgkmcnt(0)" ::: "memory");
    __builtin_amdgcn_sched_barrier(0);
    __builtin_amdgcn_s_barrier();
    if (kt + 2 < 8) STAGE(c, kt + 2);
    __builtin_amdgcn_sched_barrier(0);
    __builtin_amdgcn_s_setprio(1);
    #pragma unroll
    for (int i = 0; i < 4; ++i)
      #pragma unroll
      for (int j = 0; j < 4; ++j)
        acc[i][j] = __builtin_amdgcn_mfma_f32_16x16x32_bf16(af[1][i], bq[1][j], acc[i][j], 0, 0, 0);
    __builtin_amdgcn_s_setprio(0);
    if (kt < 7) {
      if (kt + 2 < 8) {
        asm volatile("s_waitcnt vmcnt(8)" ::: "memory");
      } else {
        asm volatile("s_waitcnt vmcnt(0)" ::: "memory");
      }
      __builtin_amdgcn_sched_barrier(0);
      __builtin_amdgcn_s_barrier();
    }
  }
  #pragma unroll
  for (int i = 0; i < 4; ++i)
    #pragma unroll
    for (int j = 0; j < 4; ++j)
      #pragma unroll
      for (int r = 0; r < 4; ++r) {
        int m = m0 + mh + i * 16 + (lane >> 4) * 4 + r;
        int n = n0 + nh + j * 16 + (lane & 15);
        float v = acc[i][j][r] + bnp[3584 + n]
                + b2f(XFh[((long)b * 1024 + m) * 512 + n]);
        Yp16[((long)b * 1024 + m) * 512 + n] = f2b(v);
      }
}

// ---------------- fused outro + final ----------------
__global__ __launch_bounds__(256) void ofinal_k(
    const bf16* __restrict__ Yp16, const bf16* __restrict__ pow16,
    const float* __restrict__ p_ob, const float* __restrict__ gacc,
    const float* __restrict__ bnp, const int* __restrict__ nvec,
    float* __restrict__ out) {
  int b = blockIdx.y;
  int m0 = blockIdx.x * 64;
  const bf16* Ab = Yp16 + (long)b * 1024 * 512;
  __shared__ bf16 Ash[64][40];
  __shared__ bf16 Bsh[64][40];
  __shared__ float ol[64][65];
  int t = threadIdx.x, w = t >> 6, lane = t & 63;
  int mq = w * 16;
  int frow = lane & 15, fko = (lane >> 4) * 8;
  f32x4 acc[4] = {};
  for (int kb = 0; kb < 512; kb += 32) {
    { int r = t >> 2, ko = (t & 3) * 8;
      *(uint4*)&Ash[r][ko] = *(const uint4*)&Ab[(long)(m0 + r) * 512 + kb + ko];
      *(uint4*)&Bsh[r][ko] = *(const uint4*)&pow16[(long)r * 512 + kb + ko]; }
    __syncthreads();
    short8 af = *(const short8*)&Ash[mq + frow][fko];
    #pragma unroll
    for (int j = 0; j < 4; ++j) {
      short8 bq = *(const short8*)&Bsh[j * 16 + frow][fko];
      acc[j] = __builtin_amdgcn_mfma_f32_16x16x32_bf16(af, bq, acc[j], 0, 0, 0);
    }
    __syncthreads();
  }
  float pr[4][4], ssl[4] = {0.f, 0.f, 0.f, 0.f};
  #pragma unroll
  for (int j = 0; j < 4; ++j) {
    float bias = p_ob[j * 16 + (lane & 15)];
    #pragma unroll
    for (int r = 0; r < 4; ++r) {
      float v = acc[j][r] + bias;
      pr[j][r] = v;
      ssl[r] = fmaf(v, v, ssl[r]);
    }
  }
  #pragma unroll
  for (int r = 0; r < 4; ++r) {
    float v = ssl[r];
    v += __shfl_xor(v, 1, 16);
    v += __shfl_xor(v, 2, 16);
    v += __shfl_xor(v, 4, 16);
    v += __shfl_xor(v, 8, 16);
    ssl[r] = v;
  }
  int nb = nvec[b];
  float gconst = bnp[3072];
  float scale[4];
  #pragma unroll
  for (int r = 0; r < 4; ++r) {
    int m = m0 + mq + (lane >> 4) * 4 + r;
    float gl = gacc[(long)b * 1024 + m] + gconst;
    float gate = 1.f / (1.f + expf(-gl));
    int ii = m >> 5, jj = m & 31;
    float maskv = (ii < nb && jj < nb) ? 1.f : 0.f;
    scale[r] = gate * maskv / fmaxf(sqrtf(ssl[r]), 1e-12f);
  }
  #pragma unroll
  for (int j = 0; j < 4; ++j)
    #pragma unroll
    for (int r = 0; r < 4; ++r)
      ol[mq + (lane >> 4) * 4 + r][j * 16 + (lane & 15)] = pr[j][r] * scale[r];
  __syncthreads();
  {
    int c = t >> 2, ms = (t & 3) * 16;
    float* op = out + ((long)b * 64 + c) * 1024 + m0 + ms;
    #pragma unroll
    for (int k = 0; k < 16; k += 4) {
      float4 v;
      v.x = ol[ms + k + 0][c];
      v.y = ol[ms + k + 1][c];
      v.z = ol[ms + k + 2][c];
      v.w = ol[ms + k + 3][c];
      *(float4*)(op + k) = v;
    }
  }
}

extern "C" void kernel_launch(void* const* d_in, const int* in_sizes, int n_in,
                              void* d_out, int out_size, void* d_ws, size_t ws_size,
                              hipStream_t stream) {
  const float* f0 = (const float*)d_in[0];
  const float* f1 = (const float*)d_in[1];
  const float* f2 = (const float*)d_in[2];
  const float* f3 = (const float*)d_in[3];
  const float* f4 = (const float*)d_in[4];
  const float* f5 = (const float*)d_in[5];
  const float* P  = (const float*)d_in[6];
  const int*   n  = (const int*)d_in[7];
  const float *g_iw=(const float*)d_in[8],  *g_ib=(const float*)d_in[9],
              *g_bg=(const float*)d_in[10], *g_bb=(const float*)d_in[11],
              *g_bm=(const float*)d_in[12], *g_bv=(const float*)d_in[13],
              *g_cw=(const float*)d_in[14], *g_cb=(const float*)d_in[15],
              *g_ow=(const float*)d_in[16], *g_ob=(const float*)d_in[17];
  const float *p_iw=(const float*)d_in[18], *p_ib=(const float*)d_in[19],
              *p_bg=(const float*)d_in[20], *p_bb=(const float*)d_in[21],
              *p_bm=(const float*)d_in[22], *p_bv=(const float*)d_in[23],
              *p_cw=(const float*)d_in[24], *p_cb=(const float*)d_in[25],
              *p_ow=(const float*)d_in[26], *p_ob=(const float*)d_in[27];
  float* out = (float*)d_out;
  char* wsb = (char*)d_ws;

  // workspace (byte offsets)
  bf16*  Sb    = (bf16*)(wsb + 0);            // 25,952,256
  bf16*  Wp    = (bf16*)(wsb + 25952256);     // 9,437,184  -> 35,389,440
  bf16*  pcw16 = (bf16*)(wsb + 35389440);     // 524,288    -> 35,913,728
  bf16*  pow16 = (bf16*)(wsb + 35913728);     // 65,536     -> 35,979,264
  bf16*  T5    = (bf16*)(wsb + 35979264);     // 8,192      -> 35,987,456
  float* bnp   = (float*)(wsb + 35987456);    // 16,384     -> 36,003,840
  float* u     = (float*)(wsb + 36003840);    // 2,048      -> 36,005,888
  float* gacc  = (float*)(wsb + 36005888);    // 32,768     -> 36,038,656
  float* A4    = (float*)(wsb + 36038656);    // 2,097,152  -> 38,135,808
  bf16*  XFh   = (bf16*)(wsb + 38135808);     // 8,388,608  -> 46,524,416
  bf16*  DH    = (bf16*)(wsb + 46524416);     // 8,388,608  -> 54,913,024
  bf16*  Yp16  = (bf16*)(wsb + 54913024);     // 8,388,608  -> 63,301,632
  // T0..T4 overlay XFh/DH/Yp16 + tail (dead until edge_k)
  bf16*  T0 = (bf16*)(wsb + 38135808);        // 16,777,216 (over XFh+DH)
  bf16*  T1 = (bf16*)(wsb + 54913024);        // 4,194,304  (over Yp16)
  bf16*  T2 = (bf16*)(wsb + 59107328);        // 2,097,152
  bf16*  T3 = (bf16*)(wsb + 61204480);        // 1,048,576
  bf16*  T4 = (bf16*)(wsb + 62253056);        //   524,288  -> 62,777,344
  bf16*  WpE = Wp + (long)2048 * LAT_;

  prep_k<<<22651, 256, 0, stream>>>(g_iw, p_iw, p_cw, p_ow, f5,
      g_bg, g_bb, g_bm, g_bv, p_bg, p_bb, p_bm, p_bv, g_ib, p_ib, p_cb,
      g_ow, g_cw, g_cb, g_ob, f0, f1, f2, f3, f4,
      Wp, pcw16, pow16, T5, bnp, u, gacc, T0, T1, T2, T3, T4);
  sample5_k<<<dim3(66, 6, 8), 256, 0, stream>>>(T0, T1, T2, T3, T4, T5, P, Sb);
  nodegemm_k<<<dim3(32, 8), 256, 0, stream>>>(Sb, Wp, A4);
  edge_k<<<dim3(8, 8, 8), 256, 0, stream>>>(Sb, WpE, bnp, A4, u, g_ow, XFh, DH, gacc);
  chorus_k<<<dim3(8, 4, 8), 256, 0, stream>>>(DH, pcw16, bnp, XFh, Yp16);
  ofinal_k<<<dim3(16, 8), 256, 0, stream>>>(Yp16, pow16, p_ob, gacc, bnp, n, out);
}

// Round 7
// 242.673 us; speedup vs baseline: 1.0437x; 1.0437x over previous
//
#include <hip/hip_runtime.h>
#include <hip/hip_bf16.h>

using bf16 = __hip_bfloat16;
using short8 = __attribute__((ext_vector_type(8))) short;
using f32x4  = __attribute__((ext_vector_type(4))) float;
typedef unsigned int u32;

#define LAT_ 1536

__device__ __forceinline__ void glds16(const bf16* g, bf16* l) {
  __builtin_amdgcn_global_load_lds(
      (const __attribute__((address_space(1))) void*)g,
      (__attribute__((address_space(3))) void*)l, 16, 0, 0);
}
__device__ __forceinline__ float b2f(bf16 x) { return __bfloat162float(x); }
__device__ __forceinline__ bf16 f2b(float x) { return __float2bfloat16(x); }

// ---------------- NCHW fp32 -> NHWC bf16 tile ----------------
template<int C, int W>
__device__ __forceinline__ void trans_tile(const float* __restrict__ src, bf16* __restrict__ dst,
                                           int b, int hw0, int c0, bf16 (*tile)[72], int t) {
  constexpr int HW = W * W;
  {
    int cl = t >> 2, h0 = (t & 3) * 16;
    const float* sp = src + (long)(b * C + c0 + cl) * HW + hw0 + h0;
    #pragma unroll
    for (int k = 0; k < 16; k += 4) {
      float4 v = *(const float4*)(sp + k);
      tile[h0 + k + 0][cl] = f2b(v.x);
      tile[h0 + k + 1][cl] = f2b(v.y);
      tile[h0 + k + 2][cl] = f2b(v.z);
      tile[h0 + k + 3][cl] = f2b(v.w);
    }
  }
  __syncthreads();
  {
    int hwl = t >> 2, cc = (t & 3) * 16;
    bf16* dp = dst + ((long)b * HW + hw0 + hwl) * C + c0 + cc;
    #pragma unroll
    for (int k = 0; k < 16; k += 2) {
      __hip_bfloat162 pr;
      pr.x = tile[hwl][cc + k];
      pr.y = tile[hwl][cc + k + 1];
      *(__hip_bfloat162*)(dp + k) = pr;
    }
  }
}

// ---------------- fused prep ----------------
// [0,18432) packA | [18432,19456) pcw | [19456,19584) pow | [19584,19600) T5
// [19600,19602) bn | [19602,19610) u | [19610] gconst | [19611,19643) gacc=0
// [19643,22651) transposes | [22651,24699) A4=0 (for split-K nodegemm atomics)
__global__ __launch_bounds__(256) void prep_k(
    const float* __restrict__ g_iw, const float* __restrict__ p_iw,
    const float* __restrict__ p_cw, const float* __restrict__ p_ow, const float* __restrict__ f5,
    const float* __restrict__ g_bg, const float* __restrict__ g_bb, const float* __restrict__ g_bm,
    const float* __restrict__ g_bv, const float* __restrict__ p_bg, const float* __restrict__ p_bb,
    const float* __restrict__ p_bm, const float* __restrict__ p_bv,
    const float* __restrict__ g_ib, const float* __restrict__ p_ib, const float* __restrict__ p_cb,
    const float* __restrict__ g_ow, const float* __restrict__ g_cw,
    const float* __restrict__ g_cb, const float* __restrict__ g_ob,
    const float* __restrict__ f0, const float* __restrict__ f1, const float* __restrict__ f2,
    const float* __restrict__ f3, const float* __restrict__ f4,
    bf16* __restrict__ Wp, bf16* __restrict__ pcw16, bf16* __restrict__ pow16,
    bf16* __restrict__ T5, float* __restrict__ bnp, float* __restrict__ u,
    float* __restrict__ gacc, float* __restrict__ A4,
    bf16* __restrict__ T0, bf16* __restrict__ T1, bf16* __restrict__ T2,
    bf16* __restrict__ T3, bf16* __restrict__ T4) {
  __shared__ bf16 tile[64][72];
  __shared__ float red[256];
  int B = blockIdx.x, t = threadIdx.x;
  if (B < 18432) {
    int seg = B / 3072;
    int idx = (B % 3072) * 256 + t;
    if (idx < 512 * 1536) {
      int r = idx / 1536, c = idx % 1536;
      const float* src; int co;
      switch (seg) {
        case 0: src = g_iw; co = 0;    break;
        case 1: src = g_iw; co = 1536; break;
        case 2: src = p_iw; co = 0;    break;
        case 3: src = p_iw; co = 1536; break;
        case 4: src = g_iw; co = 3072; break;
        default: src = p_iw; co = 3072; break;
      }
      Wp[(long)seg * 512 * 1536 + idx] = f2b(src[(long)r * 4608 + co + c]);
    }
    return;
  }
  if (B < 19456) { int idx = (B - 18432) * 256 + t; pcw16[idx] = f2b(p_cw[idx]); return; }
  if (B < 19584) { int idx = (B - 19456) * 256 + t; pow16[idx] = f2b(p_ow[idx]); return; }
  if (B < 19600) { int idx = (B - 19584) * 256 + t; T5[idx] = f2b(f5[idx]); return; }
  if (B < 19602) {
    int k = (B - 19600) * 256 + t;
    if (k < 512) {
      float sg = g_bg[k] / sqrtf(g_bv[k] + 1e-5f);
      bnp[k] = sg; bnp[512 + k] = g_bb[k] - g_bm[k] * sg;
      float sp = p_bg[k] / sqrtf(p_bv[k] + 1e-5f);
      bnp[1024 + k] = sp; bnp[1536 + k] = p_bb[k] - p_bm[k] * sp;
      bnp[2048 + k] = g_ib[k]; bnp[2560 + k] = p_ib[k];
      bnp[3584 + k] = p_cb[k];
    }
    return;
  }
  if (B < 19610) {                      // u[k] = sum_o g_ow[o]*g_cw[o*512+k]
    __shared__ float ured[4][64];
    int k0 = (B - 19602) * 64;
    int kk = t & 63, part = t >> 6;
    int k = k0 + kk;
    float s = 0.f;
    for (int o = part * 128; o < part * 128 + 128; ++o)
      s = fmaf(g_ow[o], g_cw[o * 512 + k], s);
    ured[part][kk] = s;
    __syncthreads();
    if (part == 0) u[k] = ured[0][kk] + ured[1][kk] + ured[2][kk] + ured[3][kk];
    return;
  }
  if (B == 19610) {                     // gconst = sum g_ow*g_cb + g_ob
    red[t] = g_ow[t] * g_cb[t] + g_ow[t + 256] * g_cb[t + 256];
    __syncthreads();
    for (int off = 128; off; off >>= 1) {
      if (t < off) red[t] += red[t + off];
      __syncthreads();
    }
    if (t == 0) bnp[3072] = red[0] + g_ob[0];
    return;
  }
  if (B < 19643) { int idx = (B - 19611) * 256 + t; gacc[idx] = 0.f; return; }
  if (B >= 22651) { int idx = (B - 22651) * 256 + t; A4[idx] = 0.f; return; }
  {
    int q = B - 19643;
    int b = q / 376, tt = q % 376;
    if (tt < 256)      trans_tile<64, 128>(f0, T0, b, tt * 64, 0, tile, t);
    else if (tt < 320) trans_tile<64, 64 >(f1, T1, b, (tt - 256) * 64, 0, tile, t);
    else if (tt < 352) { int z = tt - 320; trans_tile<128, 32>(f2, T2, b, (z & 15) * 64, (z >> 4) * 64, tile, t); }
    else if (tt < 368) { int z = tt - 352; trans_tile<256, 16>(f3, T3, b, (z & 3) * 64, (z >> 2) * 64, tile, t); }
    else               { int z = tt - 368; trans_tile<512, 8 >(f4, T4, b, 0, z * 64, tile, t); }
  }
}

// ---------------- sampling ----------------
__device__ __forceinline__ float blo(u32 r) { return __uint_as_float(r << 16); }
__device__ __forceinline__ float bhi(u32 r) { return __uint_as_float(r & 0xffff0000u); }

template<int C, int W>
__device__ __forceinline__ void proc2(const bf16* __restrict__ T, int b,
    const float* MX, const float* MY, bf16* __restrict__ Sb, int koff, int t) {
  constexpr int C2 = C / 2, HW = W * W;
  const bf16* Tb = T + (long)b * HW * C;
  for (int idx = t; idx < 16 * C2; idx += 256) {
    int q = idx / C2, c2 = idx % C2;
    float x = MX[q], y = MY[q];
    float fx = fminf(fmaxf(x * ((float)W / 256.f) - 0.5f, 0.f), (float)(W - 1));
    float fy = fminf(fmaxf(y * ((float)W / 256.f) - 0.5f, 0.f), (float)(W - 1));
    float x0f = floorf(fx), y0f = floorf(fy);
    float wx = fx - x0f, wy = fy - y0f;
    int x0 = (int)x0f, y0 = (int)y0f;
    int x1 = min(x0 + 1, W - 1), y1 = min(y0 + 1, W - 1);
    u32 r00 = *(const u32*)&Tb[(y0 * W + x0) * C + 2 * c2];
    u32 r01 = *(const u32*)&Tb[(y0 * W + x1) * C + 2 * c2];
    u32 r10 = *(const u32*)&Tb[(y1 * W + x0) * C + 2 * c2];
    u32 r11 = *(const u32*)&Tb[(y1 * W + x1) * C + 2 * c2];
    float w00 = (1.f - wx) * (1.f - wy), w01 = wx * (1.f - wy);
    float w10 = (1.f - wx) * wy,        w11 = wx * wy;
    float vlo = blo(r00) * w00 + blo(r01) * w01 + blo(r10) * w10 + blo(r11) * w11;
    float vhi = bhi(r00) * w00 + bhi(r01) * w01 + bhi(r10) * w10 + bhi(r11) * w11;
    __hip_bfloat162 pr;
    pr.x = f2b(vlo); pr.y = f2b(vhi);
    *(__hip_bfloat162*)&Sb[(long)q * LAT_ + koff + 2 * c2] = pr;
  }
}

__global__ __launch_bounds__(256) void sample5_k(
    const bf16* __restrict__ T0, const bf16* __restrict__ T1, const bf16* __restrict__ T2,
    const bf16* __restrict__ T3, const bf16* __restrict__ T4, const bf16* __restrict__ T5,
    const float* __restrict__ P, bf16* __restrict__ Sball) {
  int b = blockIdx.z, p0 = blockIdx.x * 16, lvl = blockIdx.y, t = threadIdx.x;
  __shared__ float Px[32], Py[32], MX[16], MY[16];
  if (t < 32) { Px[t] = P[(b * 32 + t) * 2]; Py[t] = P[(b * 32 + t) * 2 + 1]; }
  __syncthreads();
  if (t < 16) {
    int m = p0 + t;
    float x, y;
    if (m < 32) { x = Px[m]; y = Py[m]; }
    else { int ij = m - 32, i = ij >> 5, j = ij & 31;
           x = 0.5f * (Px[i] + Px[j]); y = 0.5f * (Py[i] + Py[j]); }
    MX[t] = x; MY[t] = y;
  }
  __syncthreads();
  bf16* Sb = Sball + ((long)b * 1056 + p0) * LAT_;
  switch (lvl) {
    case 0: proc2<64, 128>(T0, b, MX, MY, Sb, 0,    t); break;
    case 1: proc2<64, 64 >(T1, b, MX, MY, Sb, 64,   t); break;
    case 2: proc2<128, 32>(T2, b, MX, MY, Sb, 128,  t); break;
    case 3: proc2<256, 16>(T3, b, MX, MY, Sb, 256,  t); break;
    case 4: proc2<512, 8 >(T4, b, MX, MY, Sb, 512,  t); break;
    default:
      for (int idx = t; idx < 16 * 256; idx += 256) {
        int q = idx >> 8, c2 = idx & 255;
        *(__hip_bfloat162*)&Sb[(long)q * LAT_ + 1024 + 2 * c2] =
            *(const __hip_bfloat162*)&T5[b * 512 + 2 * c2];
      }
  }
}

// ---------------- node GEMM: A4[b][32][2048], split-K x4 ----------------
// grid (32 n-tiles, 4 K-quarters, 8 batches) = 1024 blocks (4/CU) for
// latency hiding; partials combined via fp32 atomicAdd (A4 zeroed in prep).
__global__ __launch_bounds__(256) void nodegemm_k(
    const bf16* __restrict__ Sball, const bf16* __restrict__ Wp, float* __restrict__ A4) {
  int b = blockIdx.z;
  int n0 = blockIdx.x * 64;
  int k0 = blockIdx.y * 384;
  int t = threadIdx.x, w = t >> 6, lane = t & 63;
  int nn = n0 + w * 16;
  int frow = lane & 15, fko = (lane >> 4) * 8;
  const bf16* Ab = Sball + (long)b * 1056 * LAT_;
  f32x4 acc[2] = {};
  for (int kb = k0; kb < k0 + 384; kb += 32) {
    short8 bq = *(const short8*)&Wp[(long)(nn + frow) * LAT_ + kb + fko];
    #pragma unroll
    for (int i = 0; i < 2; ++i) {
      short8 aq = *(const short8*)&Ab[(long)(i * 16 + frow) * LAT_ + kb + fko];
      acc[i] = __builtin_amdgcn_mfma_f32_16x16x32_bf16(aq, bq, acc[i], 0, 0, 0);
    }
  }
  #pragma unroll
  for (int i = 0; i < 2; ++i)
    #pragma unroll
    for (int r = 0; r < 4; ++r) {
      int m = i * 16 + (lane >> 4) * 4 + r;
      int n = nn + (lane & 15);
      atomicAdd(&A4[(long)b * 65536 + m * 2048 + n], acc[i][r]);
    }
}

// ---------------- edge GEMM: M=1024, N=1024 (g|p), K=1536 ----------------
// [R5 verified] 128x128, BK=64, dbuf + counted vmcnt + setprio. vmcnt never
// drained to 0 in main loop. Full-row 8-chunk XOR swizzle (both-sides).
__global__ __launch_bounds__(256) void edge_k(
    const bf16* __restrict__ Sball, const bf16* __restrict__ WpE,
    const float* __restrict__ bnp, const float* __restrict__ A4,
    const float* __restrict__ u, const float* __restrict__ g_ow,
    bf16* __restrict__ XFh, bf16* __restrict__ DH, float* __restrict__ gacc) {
  int b = blockIdx.z;
  int m0 = blockIdx.x * 128, n0 = blockIdx.y * 128;
  const bf16* A = Sball + (long)b * 1056 * LAT_ + 32 * LAT_;
  __shared__ bf16 Ash[2][128 * 64];
  __shared__ bf16 Bsh[2][128 * 64];
  int t = threadIdx.x, w = t >> 6, lane = t & 63;
  int mh = (w & 1) * 64, nh = (w >> 1) * 64;
  int frow = lane & 15, kq = lane >> 4;
  int srow = w * 8 + (lane >> 3), schunk = lane & 7;   // stage row/chunk
  int rx7 = frow & 7;                                  // row&7 for frag rows
  f32x4 acc[4][4] = {};

  auto STAGE = [&](int buf, int kt) {
    int kb = kt * 64;
    #pragma unroll
    for (int q = 0; q < 4; ++q) {
      int ra = q * 32 + srow;
      int sc = (schunk ^ (ra & 7)) * 8;                // inverse-swizzled src col
      glds16(&A[(long)(m0 + ra) * LAT_ + kb + sc],   &Ash[buf][ra * 64 + schunk * 8]);
      glds16(&WpE[(long)(n0 + ra) * LAT_ + kb + sc], &Bsh[buf][ra * 64 + schunk * 8]);
    }
  };

  STAGE(0, 0);
  STAGE(1, 1);
  asm volatile("s_waitcnt vmcnt(8)" ::: "memory");     // tile 0 resident
  __builtin_amdgcn_sched_barrier(0);
  __builtin_amdgcn_s_barrier();
  #pragma unroll 1
  for (int kt = 0; kt < 24; ++kt) {
    int c = kt & 1;
    short8 af[2][4], bq[2][4];
    #pragma unroll
    for (int h = 0; h < 2; ++h) {
      int s8 = (((h * 4 + kq) ^ rx7) << 3);            // swizzled read offset
      #pragma unroll
      for (int i = 0; i < 4; ++i)
        af[h][i] = *(const short8*)&Ash[c][(mh + i * 16 + frow) * 64 + s8];
      #pragma unroll
      for (int j = 0; j < 4; ++j)
        bq[h][j] = *(const short8*)&Bsh[c][(nh + j * 16 + frow) * 64 + s8];
    }
    asm volatile("s_waitcnt lgkmcnt(0)" ::: "memory"); // my reads of buf c done
    __builtin_amdgcn_sched_barrier(0);
    __builtin_amdgcn_s_barrier();                      // ALL waves done reading buf c
    if (kt + 2 < 24) STAGE(c, kt + 2);                 // overwrite buf c (async)
    __builtin_amdgcn_sched_barrier(0);
    __builtin_amdgcn_s_setprio(1);
    #pragma unroll
    for (int h = 0; h < 2; ++h)
      #pragma unroll
      for (int i = 0; i < 4; ++i)
        #pragma unroll
        for (int j = 0; j < 4; ++j)
          acc[i][j] = __builtin_amdgcn_mfma_f32_16x16x32_bf16(af[h][i], bq[h][j], acc[i][j], 0, 0, 0);
    __builtin_amdgcn_s_setprio(0);
    if (kt < 23) {
      if (kt + 2 < 24) {
        asm volatile("s_waitcnt vmcnt(8)" ::: "memory");  // tile kt+1 resident
      } else {
        asm volatile("s_waitcnt vmcnt(0)" ::: "memory");  // last tile resident
      }
      __builtin_amdgcn_sched_barrier(0);
      __builtin_amdgcn_s_barrier();
    }
  }
  if (n0 < 512) {                                     // gate half
    float pg[16];
    #pragma unroll
    for (int z = 0; z < 16; ++z) pg[z] = 0.f;
    #pragma unroll
    for (int i = 0; i < 4; ++i) {
      #pragma unroll
      for (int j = 0; j < 4; ++j) {
        int n = n0 + nh + j * 16 + (lane & 15);
        float gw = g_ow[n], uu = u[n];
        float sc2 = bnp[n], sh = bnp[512 + n], ib = bnp[2048 + n];
        #pragma unroll
        for (int r = 0; r < 4; ++r) {
          int m = m0 + mh + i * 16 + (lane >> 4) * 4 + r;
          float v = acc[i][j][r] + ib
                  + A4[((long)b * 32 + (m >> 5)) * 2048 + n]
                  + A4[((long)b * 32 + (m & 31)) * 2048 + 512 + n];
          float d = fmaxf(fmaf(v, sc2, sh), 0.f);
          pg[i * 4 + r] += gw * v + uu * d;
        }
      }
    }
    #pragma unroll
    for (int z = 0; z < 16; ++z) {
      float v = pg[z];
      v += __shfl_xor(v, 1, 16);
      v += __shfl_xor(v, 2, 16);
      v += __shfl_xor(v, 4, 16);
      v += __shfl_xor(v, 8, 16);
      pg[z] = v;
    }
    if ((lane & 15) == 0) {
      #pragma unroll
      for (int z = 0; z < 16; ++z) {
        int m = m0 + mh + (z >> 2) * 16 + (lane >> 4) * 4 + (z & 3);
        atomicAdd(&gacc[(long)b * 1024 + m], pg[z]);
      }
    }
  } else {                                            // p half: store compact
    #pragma unroll
    for (int i = 0; i < 4; ++i) {
      #pragma unroll
      for (int j = 0; j < 4; ++j) {
        int n = n0 + nh + j * 16 + (lane & 15);
        int np = n - 512;
        float sc2 = bnp[1024 + np], sh = bnp[1536 + np], ib = bnp[2048 + n];
        #pragma unroll
        for (int r = 0; r < 4; ++r) {
          int m = m0 + mh + i * 16 + (lane >> 4) * 4 + r;
          float v = acc[i][j][r] + ib
                  + A4[((long)b * 32 + (m >> 5)) * 2048 + 1024 + np]
                  + A4[((long)b * 32 + (m & 31)) * 2048 + 1536 + np];
          long e = ((long)b * 1024 + m) * 512 + np;
          XFh[e] = f2b(v);
          DH[e]  = f2b(fmaxf(fmaf(v, sc2, sh), 0.f));
        }
      }
    }
  }
}

// ---------------- chorus-p (compact), Yp16 = XFh + pcw @ DH + p_cb ----------------
// 64x128 tiles -> grid (16,4,8) = 512 blocks (2/CU, was 1/CU). R4 single-
// buffer BK=64 core + full-row swizzle. B (pcw16, 0.5MB) is L2-resident so
// the extra B re-reads don't add HBM fetch.
__global__ __launch_bounds__(256) void chorus_k(
    const bf16* __restrict__ DH, const bf16* __restrict__ pcw16,
    const float* __restrict__ bnp, const bf16* __restrict__ XFh,
    bf16* __restrict__ Yp16) {
  int b = blockIdx.z;
  int m0 = blockIdx.x * 64, n0 = blockIdx.y * 128;
  const bf16* A = DH + (long)b * 1024 * 512;
  __shared__ bf16 Ash[64 * 64];
  __shared__ bf16 Bsh[128 * 64];
  int t = threadIdx.x, w = t >> 6, lane = t & 63;
  int nh = w * 32;
  int frow = lane & 15, kq = lane >> 4;
  int srow = t >> 3, schunk = t & 7;
  int rx7 = frow & 7;
  f32x4 acc[4][2] = {};
  for (int kb = 0; kb < 512; kb += 64) {
    #pragma unroll
    for (int q = 0; q < 2; ++q) {
      int ra = q * 32 + srow;
      int sc = (schunk ^ (ra & 7)) * 8;
      glds16(&A[(long)(m0 + ra) * 512 + kb + sc], &Ash[ra * 64 + schunk * 8]);
    }
    #pragma unroll
    for (int q = 0; q < 4; ++q) {
      int ra = q * 32 + srow;
      int sc = (schunk ^ (ra & 7)) * 8;
      glds16(&pcw16[(long)(n0 + ra) * 512 + kb + sc], &Bsh[ra * 64 + schunk * 8]);
    }
    __syncthreads();
    #pragma unroll
    for (int h = 0; h < 2; ++h) {
      int s8 = (((h * 4 + kq) ^ rx7) << 3);
      short8 af[4], bq[2];
      #pragma unroll
      for (int i = 0; i < 4; ++i)
        af[i] = *(const short8*)&Ash[(i * 16 + frow) * 64 + s8];
      #pragma unroll
      for (int j = 0; j < 2; ++j)
        bq[j] = *(const short8*)&Bsh[(nh + j * 16 + frow) * 64 + s8];
      #pragma unroll
      for (int i = 0; i < 4; ++i)
        #pragma unroll
        for (int j = 0; j < 2; ++j)
          acc[i][j] = __builtin_amdgcn_mfma_f32_16x16x32_bf16(af[i], bq[j], acc[i][j], 0, 0, 0);
    }
    __syncthreads();
  }
  #pragma unroll
  for (int i = 0; i < 4; ++i)
    #pragma unroll
    for (int j = 0; j < 2; ++j)
      #pragma unroll
      for (int r = 0; r < 4; ++r) {
        int m = m0 + i * 16 + (lane >> 4) * 4 + r;
        int n = n0 + nh + j * 16 + (lane & 15);
        float v = acc[i][j][r] + bnp[3584 + n]
                + b2f(XFh[((long)b * 1024 + m) * 512 + n]);
        Yp16[((long)b * 1024 + m) * 512 + n] = f2b(v);
      }
}

// ---------------- fused outro + final ----------------
// m-tile 32 -> grid (32,8) = 256 blocks (was 128 = 0.5/CU). Waves split
// 2 row-groups x 2 col-halves; norm (ssl) combined across col-halves in LDS.
__global__ __launch_bounds__(256) void ofinal_k(
    const bf16* __restrict__ Yp16, const bf16* __restrict__ pow16,
    const float* __restrict__ p_ob, const float* __restrict__ gacc,
    const float* __restrict__ bnp, const int* __restrict__ nvec,
    float* __restrict__ out) {
  int b = blockIdx.y;
  int m0 = blockIdx.x * 32;
  const bf16* Ab = Yp16 + (long)b * 1024 * 512;
  __shared__ bf16 Ash[32][40];
  __shared__ bf16 Bsh[64][40];
  __shared__ float sred[2][2][16];
  __shared__ float ol[32][65];
  int t = threadIdx.x, w = t >> 6, lane = t & 63;
  int rowg = w & 1, colh = w >> 1;
  int mq = rowg * 16, cq = colh * 32;
  int frow = lane & 15, fko = (lane >> 4) * 8;
  f32x4 acc[2] = {};
  for (int kb = 0; kb < 512; kb += 32) {
    { int r = t >> 3, ko = (t & 7) * 4;
      *(uint2*)&Ash[r][ko] = *(const uint2*)&Ab[(long)(m0 + r) * 512 + kb + ko];
      int r2 = t >> 2, ko2 = (t & 3) * 8;
      *(uint4*)&Bsh[r2][ko2] = *(const uint4*)&pow16[(long)r2 * 512 + kb + ko2]; }
    __syncthreads();
    short8 af = *(const short8*)&Ash[mq + frow][fko];
    #pragma unroll
    for (int j = 0; j < 2; ++j) {
      short8 bq = *(const short8*)&Bsh[cq + j * 16 + frow][fko];
      acc[j] = __builtin_amdgcn_mfma_f32_16x16x32_bf16(af, bq, acc[j], 0, 0, 0);
    }
    __syncthreads();
  }
  float pr[2][4], ssl[4] = {0.f, 0.f, 0.f, 0.f};
  #pragma unroll
  for (int j = 0; j < 2; ++j) {
    float bias = p_ob[cq + j * 16 + (lane & 15)];
    #pragma unroll
    for (int r = 0; r < 4; ++r) {
      float v = acc[j][r] + bias;
      pr[j][r] = v;
      ssl[r] = fmaf(v, v, ssl[r]);
    }
  }
  #pragma unroll
  for (int r = 0; r < 4; ++r) {
    float v = ssl[r];
    v += __shfl_xor(v, 1, 16);
    v += __shfl_xor(v, 2, 16);
    v += __shfl_xor(v, 4, 16);
    v += __shfl_xor(v, 8, 16);
    ssl[r] = v;
  }
  if ((lane & 15) == 0) {
    #pragma unroll
    for (int r = 0; r < 4; ++r)
      sred[rowg][colh][(lane >> 4) * 4 + r] = ssl[r];
  }
  __syncthreads();
  int nb = nvec[b];
  float gconst = bnp[3072];
  float scale[4];
  #pragma unroll
  for (int r = 0; r < 4; ++r) {
    int row16 = (lane >> 4) * 4 + r;
    int m = m0 + mq + row16;
    float s2 = sred[rowg][0][row16] + sred[rowg][1][row16];
    float gl = gacc[(long)b * 1024 + m] + gconst;
    float gate = 1.f / (1.f + expf(-gl));
    int ii = m >> 5, jj = m & 31;
    float maskv = (ii < nb && jj < nb) ? 1.f : 0.f;
    scale[r] = gate * maskv / fmaxf(sqrtf(s2), 1e-12f);
  }
  #pragma unroll
  for (int j = 0; j < 2; ++j)
    #pragma unroll
    for (int r = 0; r < 4; ++r)
      ol[mq + (lane >> 4) * 4 + r][cq + j * 16 + (lane & 15)] = pr[j][r] * scale[r];
  __syncthreads();
  {
    int c = t >> 2, ms = (t & 3) * 8;
    float* op = out + ((long)b * 64 + c) * 1024 + m0 + ms;
    #pragma unroll
    for (int k = 0; k < 8; k += 4) {
      float4 v;
      v.x = ol[ms + k + 0][c];
      v.y = ol[ms + k + 1][c];
      v.z = ol[ms + k + 2][c];
      v.w = ol[ms + k + 3][c];
      *(float4*)(op + k) = v;
    }
  }
}

extern "C" void kernel_launch(void* const* d_in, const int* in_sizes, int n_in,
                              void* d_out, int out_size, void* d_ws, size_t ws_size,
                              hipStream_t stream) {
  const float* f0 = (const float*)d_in[0];
  const float* f1 = (const float*)d_in[1];
  const float* f2 = (const float*)d_in[2];
  const float* f3 = (const float*)d_in[3];
  const float* f4 = (const float*)d_in[4];
  const float* f5 = (const float*)d_in[5];
  const float* P  = (const float*)d_in[6];
  const int*   n  = (const int*)d_in[7];
  const float *g_iw=(const float*)d_in[8],  *g_ib=(const float*)d_in[9],
              *g_bg=(const float*)d_in[10], *g_bb=(const float*)d_in[11],
              *g_bm=(const float*)d_in[12], *g_bv=(const float*)d_in[13],
              *g_cw=(const float*)d_in[14], *g_cb=(const float*)d_in[15],
              *g_ow=(const float*)d_in[16], *g_ob=(const float*)d_in[17];
  const float *p_iw=(const float*)d_in[18], *p_ib=(const float*)d_in[19],
              *p_bg=(const float*)d_in[20], *p_bb=(const float*)d_in[21],
              *p_bm=(const float*)d_in[22], *p_bv=(const float*)d_in[23],
              *p_cw=(const float*)d_in[24], *p_cb=(const float*)d_in[25],
              *p_ow=(const float*)d_in[26], *p_ob=(const float*)d_in[27];
  float* out = (float*)d_out;
  char* wsb = (char*)d_ws;

  // workspace (byte offsets)
  bf16*  Sb    = (bf16*)(wsb + 0);            // 25,952,256
  bf16*  Wp    = (bf16*)(wsb + 25952256);     // 9,437,184  -> 35,389,440
  bf16*  pcw16 = (bf16*)(wsb + 35389440);     // 524,288    -> 35,913,728
  bf16*  pow16 = (bf16*)(wsb + 35913728);     // 65,536     -> 35,979,264
  bf16*  T5    = (bf16*)(wsb + 35979264);     // 8,192      -> 35,987,456
  float* bnp   = (float*)(wsb + 35987456);    // 16,384     -> 36,003,840
  float* u     = (float*)(wsb + 36003840);    // 2,048      -> 36,005,888
  float* gacc  = (float*)(wsb + 36005888);    // 32,768     -> 36,038,656
  float* A4    = (float*)(wsb + 36038656);    // 2,097,152  -> 38,135,808
  bf16*  XFh   = (bf16*)(wsb + 38135808);     // 8,388,608  -> 46,524,416
  bf16*  DH    = (bf16*)(wsb + 46524416);     // 8,388,608  -> 54,913,024
  bf16*  Yp16  = (bf16*)(wsb + 54913024);     // 8,388,608  -> 63,301,632
  // T0..T4 overlay XFh/DH/Yp16 + tail (dead until edge_k)
  bf16*  T0 = (bf16*)(wsb + 38135808);        // 16,777,216 (over XFh+DH)
  bf16*  T1 = (bf16*)(wsb + 54913024);        // 4,194,304  (over Yp16)
  bf16*  T2 = (bf16*)(wsb + 59107328);        // 2,097,152
  bf16*  T3 = (bf16*)(wsb + 61204480);        // 1,048,576
  bf16*  T4 = (bf16*)(wsb + 62253056);        //   524,288  -> 62,777,344
  bf16*  WpE = Wp + (long)2048 * LAT_;

  prep_k<<<24699, 256, 0, stream>>>(g_iw, p_iw, p_cw, p_ow, f5,
      g_bg, g_bb, g_bm, g_bv, p_bg, p_bb, p_bm, p_bv, g_ib, p_ib, p_cb,
      g_ow, g_cw, g_cb, g_ob, f0, f1, f2, f3, f4,
      Wp, pcw16, pow16, T5, bnp, u, gacc, A4, T0, T1, T2, T3, T4);
  sample5_k<<<dim3(66, 6, 8), 256, 0, stream>>>(T0, T1, T2, T3, T4, T5, P, Sb);
  nodegemm_k<<<dim3(32, 4, 8), 256, 0, stream>>>(Sb, Wp, A4);
  edge_k<<<dim3(8, 8, 8), 256, 0, stream>>>(Sb, WpE, bnp, A4, u, g_ow, XFh, DH, gacc);
  chorus_k<<<dim3(16, 4, 8), 256, 0, stream>>>(DH, pcw16, bnp, XFh, Yp16);
  ofinal_k<<<dim3(32, 8), 256, 0, stream>>>(Yp16, pow16, p_ob, gacc, bnp, n, out);
}